// Round 15
// baseline (205.695 us; speedup 1.0000x reference)
//
#include <hip/hip_runtime.h>
#include <stdint.h>

#define B_TOT 16384
#define F_NUM 24
#define P_NUM 276
#define BT    32          // b-rows per block (1 MFMA n-tile)
#define NTH   768         // 12 waves -> 3 waves/SIMD
#define NWV   12
#define CHNK  23          // 276 = 12 * 23, same count for every wave
#define ROWP  1544        // shorts per LDS row: 24*64 + 8 pad

typedef float f32x16 __attribute__((ext_vector_type(16)));
typedef float f32x4  __attribute__((ext_vector_type(4)));
typedef short bf16x8 __attribute__((ext_vector_type(8)));

__device__ inline unsigned short f2bf(float f) {
    unsigned u = __float_as_uint(f);
    u += 0x7fffu + ((u >> 16) & 1u);      // round-to-nearest-even
    return (unsigned short)(u >> 16);
}
__device__ inline float bf2f(unsigned short h) {
    return __uint_as_float(((unsigned)h) << 16);
}

// ---- pair schedule: 276 pairs (i-major) in 12 chunks of 23 -----------------
// epilogue flag at i-change or chunk end (partial epilogues exact: out is
// linear in V).  entry = p | (j<<9) | (i<<14) | (flag<<19)
struct Tab { int ent[NWV][CHNK]; };
constexpr Tab build_tab() {
    Tab t{};
    int ii[276] = {}, jj[276] = {};
    int n = 0;
    for (int i = 0; i < 24; ++i)
        for (int j = i + 1; j < 24; ++j) { ii[n] = i; jj[n] = j; ++n; }
    int pos = 0;
    for (int w = 0; w < NWV; ++w) {
        for (int k = 0; k < CHNK; ++k, ++pos) {
            int flag = (k == CHNK - 1) || (ii[pos + 1] != ii[pos]);
            t.ent[w][k] = pos | (jj[pos] << 9) | (ii[pos] << 14) | (flag << 19);
        }
    }
    return t;
}
__device__ __constant__ Tab gtab = build_tab();

// ---- prepass: W fp32 -> bf16 A-fragments, pair-major chunk layout ----------
// chunk(p, u) u=ks*2+m at afrag[((p*8+u)*64 + lane)*8]:
//   elem i = W[p][m*32 + (lane&31)][ks*16 + (lane>>5)*8 + i]
__global__ __launch_bounds__(256) void wprep(const float* __restrict__ W,
                                             unsigned short* __restrict__ afrag) {
    __shared__ __align__(16) unsigned short wlds[64 * 72];
    int p = blockIdx.x, t = threadIdx.x;
    const float4* src = (const float4*)(W + (size_t)p * 4096);
    #pragma unroll
    for (int c = 0; c < 4; ++c) {
        int i = t + c * 256;
        float4 v = src[i];
        int d = i >> 4;
        int e = (i & 15) * 4;
        ushort4 h; h.x=f2bf(v.x); h.y=f2bf(v.y); h.z=f2bf(v.z); h.w=f2bf(v.w);
        *(ushort4*)(&wlds[d * 72 + e]) = h;
    }
    __syncthreads();
    #pragma unroll
    for (int c = 0; c < 2; ++c) {
        int sl = t + c * 256;
        int u = sl >> 6, lane = sl & 63;
        int ks = u >> 1, m = u & 1;
        int d = m * 32 + (lane & 31);
        int e = ks * 16 + (lane >> 5) * 8;
        bf16x8 v = *(const bf16x8*)(&wlds[d * 72 + e]);
        *(bf16x8*)(afrag + ((size_t)(p * 8 + u) * 64 + lane) * 8) = v;
    }
}

#define MF(A_, B_, C_) __builtin_amdgcn_mfma_f32_32x32x16_bf16(A_, B_, C_, 0, 0, 0)

// 8x forced 16B global loads in ONE asm block; "=&v" early-clobber (round-6
// crash fix).  ROUND-15 CHANGE: `nt` (no-allocate) on every W load — the W
// stream has zero L1 reuse (each fragment read once per block), so L1
// allocation only pays the line-fill cost (~32 B/cyc/CU), which matches the
// measured 28 B/cyc wall.  nt routes around L1 to the L2-direct rate.
#define GLDW8(P_, N0,N1,N2,N3,N4,N5,N6,N7) do {                                \
    const bf16x8* b0_ = (P_);                                                  \
    const bf16x8* b1_ = (P_) + 256;                                            \
    asm volatile(                                                              \
        "global_load_dwordx4 %0, %8, off nt\n\t"                               \
        "global_load_dwordx4 %1, %8, off offset:1024 nt\n\t"                   \
        "global_load_dwordx4 %2, %8, off offset:2048 nt\n\t"                   \
        "global_load_dwordx4 %3, %8, off offset:3072 nt\n\t"                   \
        "global_load_dwordx4 %4, %9, off nt\n\t"                               \
        "global_load_dwordx4 %5, %9, off offset:1024 nt\n\t"                   \
        "global_load_dwordx4 %6, %9, off offset:2048 nt\n\t"                   \
        "global_load_dwordx4 %7, %9, off offset:3072 nt"                       \
        : "=&v"(N0),"=&v"(N1),"=&v"(N2),"=&v"(N3),                             \
          "=&v"(N4),"=&v"(N5),"=&v"(N6),"=&v"(N7)                              \
        : "v"(b0_), "v"(b1_));                                                 \
} while (0)

// epilogue: dot V (in acc) with x_i from LDS, then zero acc.  Exact under
// partial flushes (linear in V).  C-layout: a{m}[4g+j] = V[b=bcol, d=m*32+8g+4q+j]
__device__ __forceinline__ void epilog(int e, const unsigned short* xrow, int q4,
                                       f32x16& a0, f32x16& a1, float& tacc) {
    int fi = (e >> 14) & 31;
    const unsigned short* ep = xrow + fi * 64 + q4;
    #pragma unroll
    for (int g = 0; g < 4; ++g) {
        ushort4 u0 = *(const ushort4*)(ep + 8 * g);              // m=0
        tacc += a0[4*g+0]*bf2f(u0.x) + a0[4*g+1]*bf2f(u0.y)
              + a0[4*g+2]*bf2f(u0.z) + a0[4*g+3]*bf2f(u0.w);
        u0 = *(const ushort4*)(ep + 32 + 8 * g);                 // m=1
        tacc += a1[4*g+0]*bf2f(u0.x) + a1[4*g+1]*bf2f(u0.y)
              + a1[4*g+2]*bf2f(u0.z) + a1[4*g+3]*bf2f(u0.w);
    }
    #pragma unroll
    for (int k = 0; k < 16; ++k) { a0[k] = 0.f; a1[k] = 0.f; }
}

// PSTEP: consume pair E_ from {C*,X*}, prefetch pair NE_ into {N*,Y*}.
// Counted vmcnt(8): the 8 just-issued loads stay in flight across the MFMAs;
// sched_barrier(0) keeps MFMAs from hoisting above the wait (rule 18).
#define PSTEP(E_, NE_, C0,C1,C2,C3,C4,C5,C6,C7, X0,X1,X2,X3,                   \
                        N0,N1,N2,N3,N4,N5,N6,N7, Y0,Y1,Y2,Y3) do {             \
    GLDW8(afr + (size_t)((NE_) & 511) * 512 + lane,                            \
          N0,N1,N2,N3,N4,N5,N6,N7);                                            \
    { const unsigned short* bp_ = xrow + (((NE_) >> 9) & 31) * 64 + q8;        \
      Y0 = *(const bf16x8*)(bp_);      Y1 = *(const bf16x8*)(bp_ + 16);        \
      Y2 = *(const bf16x8*)(bp_ + 32); Y3 = *(const bf16x8*)(bp_ + 48); }      \
    asm volatile("s_waitcnt vmcnt(8)");                                        \
    __builtin_amdgcn_sched_barrier(0);                                         \
    __builtin_amdgcn_s_setprio(1);                                             \
    a0 = MF(C0, X0, a0); a1 = MF(C1, X0, a1);                                  \
    a0 = MF(C2, X1, a0); a1 = MF(C3, X1, a1);                                  \
    a0 = MF(C4, X2, a0); a1 = MF(C5, X2, a1);                                  \
    a0 = MF(C6, X3, a0); a1 = MF(C7, X3, a1);                                  \
    __builtin_amdgcn_s_setprio(0);                                             \
    if ((E_) & (1 << 19)) epilog(E_, xrow, q4, a0, a1, tacc);                  \
} while (0)

// tail step: no prefetch; drain everything (vmcnt(0)) so NOTHING is in flight
// at s_endpgm, then consume the last pair.
#define PSTEP_LAST(E_, C0,C1,C2,C3,C4,C5,C6,C7, X0,X1,X2,X3) do {              \
    asm volatile("s_waitcnt vmcnt(0)");                                        \
    __builtin_amdgcn_sched_barrier(0);                                         \
    __builtin_amdgcn_s_setprio(1);                                             \
    a0 = MF(C0, X0, a0); a1 = MF(C1, X0, a1);                                  \
    a0 = MF(C2, X1, a0); a1 = MF(C3, X1, a1);                                  \
    a0 = MF(C4, X2, a0); a1 = MF(C5, X2, a1);                                  \
    a0 = MF(C6, X3, a0); a1 = MF(C7, X3, a1);                                  \
    __builtin_amdgcn_s_setprio(0);                                             \
    if ((E_) & (1 << 19)) epilog(E_, xrow, q4, a0, a1, tacc);                  \
} while (0)

// ---- main kernel -----------------------------------------------------------
__global__ __launch_bounds__(NTH, 3) void fmfm_main(const float* __restrict__ x,
                                                    const unsigned short* __restrict__ afrag,
                                                    float* __restrict__ out) {
    __shared__ __align__(16) unsigned short xs[BT * ROWP];   // 98,816 B
    __shared__ float t_red[BT];
    const int tid = threadIdx.x;
    const int btile = blockIdx.x;
    const int lane = tid & 63;
    const int wv = __builtin_amdgcn_readfirstlane(tid >> 6);   // 0..11
    const int bcol = lane & 31;
    const int q = lane >> 5;
    const int q8 = q * 8, q4 = q * 4;

    if (tid < BT) t_red[tid] = 0.0f;

    const bf16x8* afr = (const bf16x8*)afrag;
    const unsigned short* xrow = xs + bcol * ROWP;

    float tacc = 0.f;
    f32x16 a0, a1;                        // acc[m]
    #pragma unroll
    for (int k = 0; k < 16; ++k) { a0[k] = 0.f; a1[k] = 0.f; }

    bf16x8 WA0,WA1,WA2,WA3,WA4,WA5,WA6,WA7;   // W buffer, ping
    bf16x8 WB0,WB1,WB2,WB3,WB4,WB5,WB6,WB7;   // W buffer, pong
    bf16x8 XA0,XA1,XA2,XA3;                   // x k-slice buffers, ping
    bf16x8 XB0,XB1,XB2,XB3;                   // x k-slice buffers, pong

    const int ef = gtab.ent[wv][0];
    // prefetch pair0's W BEFORE staging: 8 loads fly under the whole stage
    GLDW8(afr + (size_t)(ef & 511) * 512 + lane,
          WA0,WA1,WA2,WA3,WA4,WA5,WA6,WA7);

    // stage full tile: 32 rows x 6KB fp32 -> bf16 LDS, contiguous NT reads
    const float* xg = x + (size_t)btile * BT * 1536;
    #pragma unroll 4
    for (int c = 0; c < 16; ++c) {
        int idx = tid + c * NTH;         // 0..12287 float4 index
        int row = idx / 384;
        int c4  = idx - row * 384;
        f32x4 v = __builtin_nontemporal_load(
                      (const f32x4*)(xg + (size_t)row * 1536 + c4 * 4));
        ushort4 h; h.x=f2bf(v[0]); h.y=f2bf(v[1]); h.z=f2bf(v[2]); h.w=f2bf(v[3]);
        *(ushort4*)(&xs[row * ROWP + c4 * 4]) = h;
    }
    __syncthreads();

    // pair0's x k-slices
    { const unsigned short* bp = xrow + ((ef >> 9) & 31) * 64 + q8;
      XA0 = *(const bf16x8*)(bp);      XA1 = *(const bf16x8*)(bp + 16);
      XA2 = *(const bf16x8*)(bp + 32); XA3 = *(const bf16x8*)(bp + 48); }

    // CHNK = 23 (odd): 11 ping-pong double-steps over pairs 0..21, then a
    // drain-tail consumes pair 22 with no further prefetch.
    #pragma unroll 1
    for (int s = 0; s + 1 < CHNK; s += 2) {
        int e0 = gtab.ent[wv][s];
        int e1 = gtab.ent[wv][s + 1];
        int s2 = (s + 2 < CHNK) ? s + 2 : s + 1;
        int e2 = gtab.ent[wv][s2];
        PSTEP(e0, e1, WA0,WA1,WA2,WA3,WA4,WA5,WA6,WA7, XA0,XA1,XA2,XA3,
                      WB0,WB1,WB2,WB3,WB4,WB5,WB6,WB7, XB0,XB1,XB2,XB3);
        PSTEP(e1, e2, WB0,WB1,WB2,WB3,WB4,WB5,WB6,WB7, XB0,XB1,XB2,XB3,
                      WA0,WA1,WA2,WA3,WA4,WA5,WA6,WA7, XA0,XA1,XA2,XA3);
    }
    {
        int el = gtab.ent[wv][CHNK - 1];
        PSTEP_LAST(el, WA0,WA1,WA2,WA3,WA4,WA5,WA6,WA7, XA0,XA1,XA2,XA3);
    }

    atomicAdd(&t_red[bcol], tacc);
    __syncthreads();
    if (tid < BT) out[(size_t)btile * BT + tid] = t_red[tid];
}

extern "C" void kernel_launch(void* const* d_in, const int* in_sizes, int n_in,
                              void* d_out, int out_size, void* d_ws, size_t ws_size,
                              hipStream_t stream) {
    const float* x = (const float*)d_in[0];
    const float* W = (const float*)d_in[1];
    float* out = (float*)d_out;
    unsigned short* afrag = (unsigned short*)d_ws;   // 2.26 MB scratch
    wprep<<<P_NUM, 256, 0, stream>>>(W, afrag);
    fmfm_main<<<B_TOT / BT, NTH, 0, stream>>>(x, afrag, out);
}

// Round 16
// 182.532 us; speedup vs baseline: 1.1269x; 1.1269x over previous
//
#include <hip/hip_runtime.h>
#include <stdint.h>

#define B_TOT 16384
#define F_NUM 24
#define P_NUM 276
#define BT    32          // b-rows per block (1 MFMA n-tile)
#define NTH   768         // 12 waves -> 3 waves/SIMD
#define NWV   12
#define CHNK  23          // 276 = 12 * 23, same count for every wave
#define ROWP  1544        // shorts per LDS row: 24*64 + 8 pad

typedef float f32x16 __attribute__((ext_vector_type(16)));
typedef float f32x4  __attribute__((ext_vector_type(4)));
typedef short bf16x8 __attribute__((ext_vector_type(8)));

__device__ inline unsigned short f2bf(float f) {
    unsigned u = __float_as_uint(f);
    u += 0x7fffu + ((u >> 16) & 1u);      // round-to-nearest-even
    return (unsigned short)(u >> 16);
}
__device__ inline float bf2f(unsigned short h) {
    return __uint_as_float(((unsigned)h) << 16);
}

// ---- pair schedule: 276 pairs (i-major) in 12 chunks of 23 -----------------
// epilogue flag at i-change or chunk end (partial epilogues exact: out is
// linear in V).  entry = p | (j<<9) | (i<<14) | (flag<<19)
struct Tab { int ent[NWV][CHNK]; };
constexpr Tab build_tab() {
    Tab t{};
    int ii[276] = {}, jj[276] = {};
    int n = 0;
    for (int i = 0; i < 24; ++i)
        for (int j = i + 1; j < 24; ++j) { ii[n] = i; jj[n] = j; ++n; }
    int pos = 0;
    for (int w = 0; w < NWV; ++w) {
        for (int k = 0; k < CHNK; ++k, ++pos) {
            int flag = (k == CHNK - 1) || (ii[pos + 1] != ii[pos]);
            t.ent[w][k] = pos | (jj[pos] << 9) | (ii[pos] << 14) | (flag << 19);
        }
    }
    return t;
}
__device__ __constant__ Tab gtab = build_tab();

// ---- prepass: W fp32 -> bf16 A-fragments, pair-major chunk layout ----------
// chunk(p, u) u=ks*2+m at afrag[((p*8+u)*64 + lane)*8]:
//   elem i = W[p][m*32 + (lane&31)][ks*16 + (lane>>5)*8 + i]
__global__ __launch_bounds__(256) void wprep(const float* __restrict__ W,
                                             unsigned short* __restrict__ afrag) {
    __shared__ __align__(16) unsigned short wlds[64 * 72];
    int p = blockIdx.x, t = threadIdx.x;
    const float4* src = (const float4*)(W + (size_t)p * 4096);
    #pragma unroll
    for (int c = 0; c < 4; ++c) {
        int i = t + c * 256;
        float4 v = src[i];
        int d = i >> 4;
        int e = (i & 15) * 4;
        ushort4 h; h.x=f2bf(v.x); h.y=f2bf(v.y); h.z=f2bf(v.z); h.w=f2bf(v.w);
        *(ushort4*)(&wlds[d * 72 + e]) = h;
    }
    __syncthreads();
    #pragma unroll
    for (int c = 0; c < 2; ++c) {
        int sl = t + c * 256;
        int u = sl >> 6, lane = sl & 63;
        int ks = u >> 1, m = u & 1;
        int d = m * 32 + (lane & 31);
        int e = ks * 16 + (lane >> 5) * 8;
        bf16x8 v = *(const bf16x8*)(&wlds[d * 72 + e]);
        *(bf16x8*)(afrag + ((size_t)(p * 8 + u) * 64 + lane) * 8) = v;
    }
}

#define MF(A_, B_, C_) __builtin_amdgcn_mfma_f32_32x32x16_bf16(A_, B_, C_, 0, 0, 0)

// 8x forced 16B global loads in ONE asm block; "=&v" early-clobber (round-6
// crash fix).  ROUND-16 CHANGE: `sc0` (SE scope) on every W load — scope
// above CU means the load neither hits nor allocates the CU-local vector L1
// (skips the L1 line-fill path, the candidate ~28-32 B/cyc wall) while the
// line remains a NORMAL temporal L2 line.  This is the clean L1-bypass that
// round-15's `nt` was not (nt = hierarchy-wide non-temporal -> L2/L3
// eviction -> FETCH +16-21 MB, 91 us regression).
#define GLDW8(P_, N0,N1,N2,N3,N4,N5,N6,N7) do {                                \
    const bf16x8* b0_ = (P_);                                                  \
    const bf16x8* b1_ = (P_) + 256;                                            \
    asm volatile(                                                              \
        "global_load_dwordx4 %0, %8, off sc0\n\t"                              \
        "global_load_dwordx4 %1, %8, off offset:1024 sc0\n\t"                  \
        "global_load_dwordx4 %2, %8, off offset:2048 sc0\n\t"                  \
        "global_load_dwordx4 %3, %8, off offset:3072 sc0\n\t"                  \
        "global_load_dwordx4 %4, %9, off sc0\n\t"                              \
        "global_load_dwordx4 %5, %9, off offset:1024 sc0\n\t"                  \
        "global_load_dwordx4 %6, %9, off offset:2048 sc0\n\t"                  \
        "global_load_dwordx4 %7, %9, off offset:3072 sc0"                      \
        : "=&v"(N0),"=&v"(N1),"=&v"(N2),"=&v"(N3),                             \
          "=&v"(N4),"=&v"(N5),"=&v"(N6),"=&v"(N7)                              \
        : "v"(b0_), "v"(b1_));                                                 \
} while (0)

// epilogue: dot V (in acc) with x_i from LDS, then zero acc.  Exact under
// partial flushes (linear in V).  C-layout: a{m}[4g+j] = V[b=bcol, d=m*32+8g+4q+j]
__device__ __forceinline__ void epilog(int e, const unsigned short* xrow, int q4,
                                       f32x16& a0, f32x16& a1, float& tacc) {
    int fi = (e >> 14) & 31;
    const unsigned short* ep = xrow + fi * 64 + q4;
    #pragma unroll
    for (int g = 0; g < 4; ++g) {
        ushort4 u0 = *(const ushort4*)(ep + 8 * g);              // m=0
        tacc += a0[4*g+0]*bf2f(u0.x) + a0[4*g+1]*bf2f(u0.y)
              + a0[4*g+2]*bf2f(u0.z) + a0[4*g+3]*bf2f(u0.w);
        u0 = *(const ushort4*)(ep + 32 + 8 * g);                 // m=1
        tacc += a1[4*g+0]*bf2f(u0.x) + a1[4*g+1]*bf2f(u0.y)
              + a1[4*g+2]*bf2f(u0.z) + a1[4*g+3]*bf2f(u0.w);
    }
    #pragma unroll
    for (int k = 0; k < 16; ++k) { a0[k] = 0.f; a1[k] = 0.f; }
}

// PSTEP: consume pair E_ from {C*,X*}, prefetch pair NE_ into {N*,Y*}.
// Counted vmcnt(8): the 8 just-issued loads stay in flight across the MFMAs;
// sched_barrier(0) keeps MFMAs from hoisting above the wait (rule 18).
#define PSTEP(E_, NE_, C0,C1,C2,C3,C4,C5,C6,C7, X0,X1,X2,X3,                   \
                        N0,N1,N2,N3,N4,N5,N6,N7, Y0,Y1,Y2,Y3) do {             \
    GLDW8(afr + (size_t)((NE_) & 511) * 512 + lane,                            \
          N0,N1,N2,N3,N4,N5,N6,N7);                                            \
    { const unsigned short* bp_ = xrow + (((NE_) >> 9) & 31) * 64 + q8;        \
      Y0 = *(const bf16x8*)(bp_);      Y1 = *(const bf16x8*)(bp_ + 16);        \
      Y2 = *(const bf16x8*)(bp_ + 32); Y3 = *(const bf16x8*)(bp_ + 48); }      \
    asm volatile("s_waitcnt vmcnt(8)");                                        \
    __builtin_amdgcn_sched_barrier(0);                                         \
    __builtin_amdgcn_s_setprio(1);                                             \
    a0 = MF(C0, X0, a0); a1 = MF(C1, X0, a1);                                  \
    a0 = MF(C2, X1, a0); a1 = MF(C3, X1, a1);                                  \
    a0 = MF(C4, X2, a0); a1 = MF(C5, X2, a1);                                  \
    a0 = MF(C6, X3, a0); a1 = MF(C7, X3, a1);                                  \
    __builtin_amdgcn_s_setprio(0);                                             \
    if ((E_) & (1 << 19)) epilog(E_, xrow, q4, a0, a1, tacc);                  \
} while (0)

// tail step: no prefetch; drain everything (vmcnt(0)) so NOTHING is in flight
// at s_endpgm, then consume the last pair.
#define PSTEP_LAST(E_, C0,C1,C2,C3,C4,C5,C6,C7, X0,X1,X2,X3) do {              \
    asm volatile("s_waitcnt vmcnt(0)");                                        \
    __builtin_amdgcn_sched_barrier(0);                                         \
    __builtin_amdgcn_s_setprio(1);                                             \
    a0 = MF(C0, X0, a0); a1 = MF(C1, X0, a1);                                  \
    a0 = MF(C2, X1, a0); a1 = MF(C3, X1, a1);                                  \
    a0 = MF(C4, X2, a0); a1 = MF(C5, X2, a1);                                  \
    a0 = MF(C6, X3, a0); a1 = MF(C7, X3, a1);                                  \
    __builtin_amdgcn_s_setprio(0);                                             \
    if ((E_) & (1 << 19)) epilog(E_, xrow, q4, a0, a1, tacc);                  \
} while (0)

// ---- main kernel -----------------------------------------------------------
__global__ __launch_bounds__(NTH, 3) void fmfm_main(const float* __restrict__ x,
                                                    const unsigned short* __restrict__ afrag,
                                                    float* __restrict__ out) {
    __shared__ __align__(16) unsigned short xs[BT * ROWP];   // 98,816 B
    __shared__ float t_red[BT];
    const int tid = threadIdx.x;
    const int btile = blockIdx.x;
    const int lane = tid & 63;
    const int wv = __builtin_amdgcn_readfirstlane(tid >> 6);   // 0..11
    const int bcol = lane & 31;
    const int q = lane >> 5;
    const int q8 = q * 8, q4 = q * 4;

    if (tid < BT) t_red[tid] = 0.0f;

    const bf16x8* afr = (const bf16x8*)afrag;
    const unsigned short* xrow = xs + bcol * ROWP;

    float tacc = 0.f;
    f32x16 a0, a1;                        // acc[m]
    #pragma unroll
    for (int k = 0; k < 16; ++k) { a0[k] = 0.f; a1[k] = 0.f; }

    bf16x8 WA0,WA1,WA2,WA3,WA4,WA5,WA6,WA7;   // W buffer, ping
    bf16x8 WB0,WB1,WB2,WB3,WB4,WB5,WB6,WB7;   // W buffer, pong
    bf16x8 XA0,XA1,XA2,XA3;                   // x k-slice buffers, ping
    bf16x8 XB0,XB1,XB2,XB3;                   // x k-slice buffers, pong

    const int ef = gtab.ent[wv][0];
    // prefetch pair0's W BEFORE staging: 8 loads fly under the whole stage
    GLDW8(afr + (size_t)(ef & 511) * 512 + lane,
          WA0,WA1,WA2,WA3,WA4,WA5,WA6,WA7);

    // stage full tile: 32 rows x 6KB fp32 -> bf16 LDS, contiguous NT reads
    const float* xg = x + (size_t)btile * BT * 1536;
    #pragma unroll 4
    for (int c = 0; c < 16; ++c) {
        int idx = tid + c * NTH;         // 0..12287 float4 index
        int row = idx / 384;
        int c4  = idx - row * 384;
        f32x4 v = __builtin_nontemporal_load(
                      (const f32x4*)(xg + (size_t)row * 1536 + c4 * 4));
        ushort4 h; h.x=f2bf(v[0]); h.y=f2bf(v[1]); h.z=f2bf(v[2]); h.w=f2bf(v[3]);
        *(ushort4*)(&xs[row * ROWP + c4 * 4]) = h;
    }
    __syncthreads();

    // pair0's x k-slices
    { const unsigned short* bp = xrow + ((ef >> 9) & 31) * 64 + q8;
      XA0 = *(const bf16x8*)(bp);      XA1 = *(const bf16x8*)(bp + 16);
      XA2 = *(const bf16x8*)(bp + 32); XA3 = *(const bf16x8*)(bp + 48); }

    // CHNK = 23 (odd): 11 ping-pong double-steps over pairs 0..21, then a
    // drain-tail consumes pair 22 with no further prefetch.
    #pragma unroll 1
    for (int s = 0; s + 1 < CHNK; s += 2) {
        int e0 = gtab.ent[wv][s];
        int e1 = gtab.ent[wv][s + 1];
        int s2 = (s + 2 < CHNK) ? s + 2 : s + 1;
        int e2 = gtab.ent[wv][s2];
        PSTEP(e0, e1, WA0,WA1,WA2,WA3,WA4,WA5,WA6,WA7, XA0,XA1,XA2,XA3,
                      WB0,WB1,WB2,WB3,WB4,WB5,WB6,WB7, XB0,XB1,XB2,XB3);
        PSTEP(e1, e2, WB0,WB1,WB2,WB3,WB4,WB5,WB6,WB7, XB0,XB1,XB2,XB3,
                      WA0,WA1,WA2,WA3,WA4,WA5,WA6,WA7, XA0,XA1,XA2,XA3);
    }
    {
        int el = gtab.ent[wv][CHNK - 1];
        PSTEP_LAST(el, WA0,WA1,WA2,WA3,WA4,WA5,WA6,WA7, XA0,XA1,XA2,XA3);
    }

    atomicAdd(&t_red[bcol], tacc);
    __syncthreads();
    if (tid < BT) out[(size_t)btile * BT + tid] = t_red[tid];
}

extern "C" void kernel_launch(void* const* d_in, const int* in_sizes, int n_in,
                              void* d_out, int out_size, void* d_ws, size_t ws_size,
                              hipStream_t stream) {
    const float* x = (const float*)d_in[0];
    const float* W = (const float*)d_in[1];
    float* out = (float*)d_out;
    unsigned short* afrag = (unsigned short*)d_ws;   // 2.26 MB scratch
    wprep<<<P_NUM, 256, 0, stream>>>(W, afrag);
    fmfm_main<<<B_TOT / BT, NTH, 0, stream>>>(x, afrag, out);
}